// Round 1
// baseline (8731.200 us; speedup 1.0000x reference)
//
#include <hip/hip_runtime.h>
#include <math.h>

// ---------------- problem constants ----------------
#define NNv    1024
#define BSZ    32
#define NINv   784
#define NOUTv  10
#define ALPHAc 0.9f
#define DTc    0.05f
#define EPSc   0.05f
#define MAXST  1000

// ---------------- launch geometry ----------------
#define GRIDv  256      // 1 block per CU, uniform work
#define THRv   512      // 8 waves

// ---------------- workspace layout (float indices) ----------------
#define WS_XIN   0        // [1024][32] x_in (transposed, i-major)
#define WS_H0A   32768
#define WS_H0B   65536
#define WS_H1A   98304
#define WS_H1B   131072
#define WS_PA    163840   // [8][1024][32] partials layer0
#define WS_PB    425984   // [8][1024][32] partials layer1
#define WS_CTRL  688128   // uints: [0..2] delta slots, [16] barrier cnt, [32] barrier gen

struct Prm {
  const float *W_in, *b_in, *W_rec, *mask, *b_rec, *W_out, *b_out, *xin;
  float *h0a, *h0b, *h1a, *h1b, *PA, *PB, *out;
  unsigned *ctrl;
};

__device__ __forceinline__ void fma4(float4& a, float4 h, float w) {
  a.x = fmaf(h.x, w, a.x); a.y = fmaf(h.y, w, a.y);
  a.z = fmaf(h.z, w, a.z); a.w = fmaf(h.w, w, a.w);
}
__device__ __forceinline__ void red4(float4& a, int m) {
  a.x += __shfl_xor(a.x, m); a.y += __shfl_xor(a.y, m);
  a.z += __shfl_xor(a.z, m); a.w += __shfl_xor(a.w, m);
}

// sense-reversing grid barrier (all 256 blocks co-resident by construction)
__device__ __forceinline__ void gsync(unsigned* cnt, unsigned* gen) {
  __syncthreads();
  if (threadIdx.x == 0) {
    __threadfence();  // release: publish this block's writes device-wide
    unsigned g = __hip_atomic_load(gen, __ATOMIC_RELAXED, __HIP_MEMORY_SCOPE_AGENT);
    unsigned a = __hip_atomic_fetch_add(cnt, 1u, __ATOMIC_RELAXED, __HIP_MEMORY_SCOPE_AGENT);
    if (a == GRIDv - 1) {
      __hip_atomic_store(cnt, 0u, __ATOMIC_RELAXED, __HIP_MEMORY_SCOPE_AGENT);
      __hip_atomic_store(gen, g + 1u, __ATOMIC_RELEASE, __HIP_MEMORY_SCOPE_AGENT); // orders cnt reset before
    } else {
      while (__hip_atomic_load(gen, __ATOMIC_RELAXED, __HIP_MEMORY_SCOPE_AGENT) == g)
        __builtin_amdgcn_s_sleep(1);
    }
    __threadfence();  // acquire: see other blocks' writes
  }
  __syncthreads();
}

// x_in = X @ W_input^T + b_input, stored [i][b]; also zero h buffers + control words
__global__ __launch_bounds__(256) void k_xin(const float* X, const float* Wi, const float* bi,
                                             float* xin, float* h0a, float* h1a, unsigned* ctrl) {
  int i  = blockIdx.x;
  int b  = threadIdx.x & 31;
  int fs = threadIdx.x >> 5;           // 8 f-slices
  const float* xr = X  + b * NINv;
  const float* wr = Wi + i * NINv;
  float acc = 0.f;
  for (int f = fs; f < NINv; f += 8) acc = fmaf(xr[f], wr[f], acc);
  __shared__ float red[8][32];
  red[fs][b] = acc;
  __syncthreads();
  if (threadIdx.x < 32) {
    float s = bi[i];
    #pragma unroll
    for (int q = 0; q < 8; ++q) s += red[q][threadIdx.x];
    xin[i*BSZ + threadIdx.x] = s;
    h0a[i*BSZ + threadIdx.x] = 0.f;   // h0 initial state (parity-0 buffer)
    h1a[i*BSZ + threadIdx.x] = 0.f;   // h1 initial state
  }
  if (i == 0 && threadIdx.x < 64) ctrl[threadIdx.x] = 0u;
}

// Persistent kernel: device-side while-loop, 2 grid syncs per Euler step.
// Pipeline: iteration t computes A-mm(t) and B-mm(t-1) [M phase], then
// A-epi(t) and B-epi(t-1) [E phase]; delta(t-1) is complete after E, checked post-sync.
__global__ __launch_bounds__(THRv, 2) void k_main(Prm p) {
  const int tid  = threadIdx.x;
  const int bid  = blockIdx.x;
  const int wv   = tid >> 6;        // wave 0..7 -> i-quad within tile
  const int lane = tid & 63;
  const int lg   = lane & 7;        // b-quad 0..7
  const int jq   = lane >> 3;       // j-slice 0..7 within tile
  const int ia   = bid & 31;        // i-tile (32 tiles of 32 rows)
  const int ja   = bid >> 5;        // j-tile (8 tiles of 128 cols)

  __shared__ __align__(16) float lds_a [4096];  // Wm0  tile [jl][il] (quad-swizzled)
  __shared__ __align__(16) float lds_b1[4096];  // Win1 tile
  __shared__ __align__(16) float lds_bm[4096];  // Wm1  tile
  __shared__ unsigned bm0, bm1;

  // ---- stage weight tiles into LDS once (quad swizzle: phys quad = (il>>2 + jl>>4) & 7) ----
  {
    const float* wr0 = p.W_rec;
    const float* mk0 = p.mask;
    const float* wi1 = p.W_in  + NNv*NNv;
    const float* wr1 = p.W_rec + NNv*NNv;
    const float* mk1 = p.mask  + NNv*NNv;
    for (int idx = tid; idx < 4096; idx += THRv) {
      int il = idx & 31, jl = idx >> 5;
      int g  = (ia*32 + il)*NNv + (ja*128 + jl);
      int ph = jl*32 + ((((il>>2) + (jl>>4)) & 7) << 2) + (il & 3);
      lds_a [ph] = wr0[g] * mk0[g];
      lds_b1[ph] = wi1[g];
      lds_bm[ph] = wr1[g] * mk1[g];
    }
  }
  __syncthreads();

  unsigned* dslot = p.ctrl;
  unsigned* cnt   = p.ctrl + 16;
  unsigned* gen   = p.ctrl + 32;
  const float4* A4  = (const float4*)lds_a;
  const float4* B14 = (const float4*)lds_b1;
  const float4* BM4 = (const float4*)lds_bm;
  float*  h0buf[2] = { p.h0a, p.h0b };
  float*  h1buf[2] = { p.h1a, p.h1b };
  float4* PA4 = (float4*)p.PA;
  float4* PB4 = (float4*)p.PB;

  int t = 1;
  int K = MAXST;
  for (;;) {
    if (tid == 0) { bm0 = 0u; bm1 = 0u; }
    const float* h0r = h0buf[(t-1) & 1];      // h0(t-1)
    const float* h1r = h1buf[t & 1];          // h1(t-2)
    const float4* h0r4 = (const float4*)h0r;
    const float4* h1r4 = (const float4*)h1r;

    // ================= M phase =================
    { // A-mm(t): partial of h0(t-1) @ Wm0^T for tile (ia, ja)
      float4 a0 = {0,0,0,0}, a1 = a0, a2 = a0, a3 = a0;
      #pragma unroll
      for (int s = 0; s < 16; ++s) {
        int jl = (jq << 4) + s;
        float4 wq = A4[(jl << 3) + ((wv + jq) & 7)];          // conflict-free broadcast
        float4 hq = h0r4[(((ja << 7) + jl) << 3) + lg];       // 16B/lane coalesced
        fma4(a0, hq, wq.x); fma4(a1, hq, wq.y); fma4(a2, hq, wq.z); fma4(a3, hq, wq.w);
      }
      red4(a0,8); red4(a0,16); red4(a0,32);
      red4(a1,8); red4(a1,16); red4(a1,32);
      red4(a2,8); red4(a2,16); red4(a2,32);
      red4(a3,8); red4(a3,16); red4(a3,32);
      if (jq == 0) {
        int ibase = (ja << 10) + (ia << 5) + (wv << 2);
        PA4[(ibase+0)*8 + lg] = a0;
        PA4[(ibase+1)*8 + lg] = a1;
        PA4[(ibase+2)*8 + lg] = a2;
        PA4[(ibase+3)*8 + lg] = a3;
      }
    }
    if (t >= 2) { // B-mm(t-1): h0(t-1)@Win1^T + h1(t-2)@Wm1^T
      float4 a0 = {0,0,0,0}, a1 = a0, a2 = a0, a3 = a0;
      #pragma unroll
      for (int s = 0; s < 16; ++s) {
        int jl = (jq << 4) + s;
        int q  = (jl << 3) + ((wv + jq) & 7);
        float4 w1 = B14[q];
        float4 wm = BM4[q];
        int hi = (((ja << 7) + jl) << 3) + lg;
        float4 ha = h0r4[hi];
        float4 hb = h1r4[hi];
        fma4(a0, ha, w1.x); fma4(a1, ha, w1.y); fma4(a2, ha, w1.z); fma4(a3, ha, w1.w);
        fma4(a0, hb, wm.x); fma4(a1, hb, wm.y); fma4(a2, hb, wm.z); fma4(a3, hb, wm.w);
      }
      red4(a0,8); red4(a0,16); red4(a0,32);
      red4(a1,8); red4(a1,16); red4(a1,32);
      red4(a2,8); red4(a2,16); red4(a2,32);
      red4(a3,8); red4(a3,16); red4(a3,32);
      if (jq == 0) {
        int ibase = (ja << 10) + (ia << 5) + (wv << 2);
        PB4[(ibase+0)*8 + lg] = a0;
        PB4[(ibase+1)*8 + lg] = a1;
        PB4[(ibase+2)*8 + lg] = a2;
        PB4[(ibase+3)*8 + lg] = a3;
      }
    }
    gsync(cnt, gen);

    // ================= E phase ================= (block bid owns i in [bid*4, bid*4+4))
    if (tid < 128) {           // A-epi(t)
      int il = tid >> 5, b = tid & 31;
      int i  = (bid << 2) + il;
      float s = 0.f;
      #pragma unroll
      for (int jg = 0; jg < 8; ++jg) s += p.PA[((jg << 10) + i)*BSZ + b];
      s += p.xin[i*BSZ + b] + p.b_rec[i];
      float ho = h0r[i*BSZ + b];
      float dh = fmaf(-ALPHAc, ho, sinf(s));
      h0buf[t & 1][i*BSZ + b] = fmaf(dh, DTc, ho);
      atomicMax(&bm0, __float_as_uint(fabsf(dh)));
    } else if (tid < 256 && t >= 2) {  // B-epi(t-1)
      int t2 = tid - 128;
      int il = t2 >> 5, b = t2 & 31;
      int i  = (bid << 2) + il;
      float s = 0.f;
      #pragma unroll
      for (int jg = 0; jg < 8; ++jg) s += p.PB[((jg << 10) + i)*BSZ + b];
      s += p.b_in[NNv + i] + p.b_rec[NNv + i];
      float ho = h1r[i*BSZ + b];                   // h1(t-2)
      float dh = fmaf(-ALPHAc, ho, sinf(s));
      h1buf[(t-1) & 1][i*BSZ + b] = fmaf(dh, DTc, ho);
      atomicMax(&bm1, __float_as_uint(fabsf(dh)));
    }
    __syncthreads();
    if (tid == 0) {
      atomicMax(&dslot[t % 3], bm0);                       // dh0(t)
      if (t >= 2) atomicMax(&dslot[(t-1) % 3], bm1);       // dh1(t-1)
      if (bid == 0)                                        // pre-zero slot for step t+1 (untouched this iter)
        __hip_atomic_store(&dslot[(t+1) % 3], 0u, __ATOMIC_RELAXED, __HIP_MEMORY_SCOPE_AGENT);
    }
    gsync(cnt, gen);

    if (t >= 2) {
      unsigned db = __hip_atomic_load(&dslot[(t-1) % 3], __ATOMIC_RELAXED, __HIP_MEMORY_SCOPE_AGENT);
      float d = __uint_as_float(db);
      if (!(d >= EPSc) || (t - 1) >= MAXST) { K = t - 1; break; }   // NaN-safe, matches JAX cond
    }
    ++t;
  }

  // ---- output: out = h1(K) @ W_out^T + b_out  (blocks 0..9, one output column each)
  if (bid < NOUTv) {
    const float* h1f = h1buf[K & 1];
    int o  = bid;
    int b  = tid & 31;
    int js = tid >> 5;                 // 16 i-slices of 64
    float acc = 0.f;
    for (int q = 0; q < 64; ++q) {
      int i = (js << 6) + q;
      acc = fmaf(h1f[i*BSZ + b], p.W_out[o*NNv + i], acc);
    }
    float* sr = lds_a;                 // weights no longer needed
    sr[js*32 + b] = acc;
    __syncthreads();
    if (tid < 32) {
      float s = p.b_out[o];
      #pragma unroll
      for (int q = 0; q < 16; ++q) s += sr[q*32 + tid];
      p.out[tid*NOUTv + o] = s;        // out[b][o]
    }
  }
}

extern "C" void kernel_launch(void* const* d_in, const int* in_sizes, int n_in,
                              void* d_out, int out_size, void* d_ws, size_t ws_size,
                              hipStream_t stream) {
  const float* X       = (const float*)d_in[0];
  const float* W_input = (const float*)d_in[1];
  const float* b_input = (const float*)d_in[2];
  const float* W_in    = (const float*)d_in[3];
  const float* b_in    = (const float*)d_in[4];
  const float* W_rec   = (const float*)d_in[5];
  const float* mask    = (const float*)d_in[6];
  const float* b_rec   = (const float*)d_in[7];
  const float* W_out   = (const float*)d_in[8];
  const float* b_out   = (const float*)d_in[9];
  (void)in_sizes; (void)n_in; (void)out_size; (void)ws_size;

  float* ws = (float*)d_ws;
  Prm p;
  p.W_in  = W_in;  p.b_in  = b_in;  p.W_rec = W_rec; p.mask = mask;
  p.b_rec = b_rec; p.W_out = W_out; p.b_out = b_out;
  p.xin = ws + WS_XIN;
  p.h0a = ws + WS_H0A; p.h0b = ws + WS_H0B;
  p.h1a = ws + WS_H1A; p.h1b = ws + WS_H1B;
  p.PA  = ws + WS_PA;  p.PB  = ws + WS_PB;
  p.ctrl = (unsigned*)(ws + WS_CTRL);
  p.out  = (float*)d_out;

  k_xin<<<NNv, 256, 0, stream>>>(X, W_input, b_input,
                                 (float*)p.xin, p.h0a, p.h1a, p.ctrl);
  k_main<<<GRIDv, THRv, 0, stream>>>(p);
}

// Round 2
// 4834.882 us; speedup vs baseline: 1.8059x; 1.8059x over previous
//
#include <hip/hip_runtime.h>
#include <math.h>

// ---------------- problem constants ----------------
#define NNv    1024
#define BSZ    32
#define NINv   784
#define NOUTv  10
#define ALPHAc 0.9f
#define DTc    0.05f
#define EPSc   0.05f
#define MAXST  1000

// ---------------- launch geometry ----------------
#define GRIDv  256      // 1 block per CU; each block owns 4 rows of both layers
#define THRv   512      // 8 waves

// ---------------- workspace layout (float indices) ----------------
#define WS_XIN 0
#define WS_H0A 32768
#define WS_H0B 65536
#define WS_H1A 98304
#define WS_H1B 131072
#define WS_FLG 163840   // byte 655360: flag0[2][256] u64, then flag1[2][256] u64

typedef unsigned long long u64;

struct Prm {
  const float *W_in, *b_in, *W_rec, *mask, *b_rec, *W_out, *b_out, *xin;
  float *h0a, *h0b, *h1a, *h1b, *out;
  u64 *flag0, *flag1;
};

__device__ __forceinline__ void fma4(float4& a, const float4 h, const float w) {
  a.x = fmaf(h.x, w, a.x); a.y = fmaf(h.y, w, a.y);
  a.z = fmaf(h.z, w, a.z); a.w = fmaf(h.w, w, a.w);
}
__device__ __forceinline__ void red4(float4& a, int m) {
  a.x += __shfl_xor(a.x, m); a.y += __shfl_xor(a.y, m);
  a.z += __shfl_xor(a.z, m); a.w += __shfl_xor(a.w, m);
}
__device__ __forceinline__ unsigned amax4bits(const float4 d) {
  float m = fmaxf(fmaxf(fabsf(d.x), fabsf(d.y)), fmaxf(fabsf(d.z), fabsf(d.w)));
  return __float_as_uint(m);   // deltas are finite & >=0: uint compare == float compare, NaN sorts高
}

// x_in = X @ W_input^T + b_input, stored [i][b]; zero all four h state buffers
__global__ __launch_bounds__(256) void k_xin(const float* X, const float* Wi, const float* bi,
                                             float* xin, float* h0a, float* h0b,
                                             float* h1a, float* h1b) {
  int i  = blockIdx.x;
  int b  = threadIdx.x & 31;
  int fs = threadIdx.x >> 5;
  const float* xr = X  + b * NINv;
  const float* wr = Wi + i * NINv;
  float acc = 0.f;
  for (int f = fs; f < NINv; f += 8) acc = fmaf(xr[f], wr[f], acc);
  __shared__ float red[8][32];
  red[fs][b] = acc;
  __syncthreads();
  if (threadIdx.x < 32) {
    float s = bi[i];
    #pragma unroll
    for (int q = 0; q < 8; ++q) s += red[q][threadIdx.x];
    int off = i * BSZ + threadIdx.x;
    xin[off] = s;
    h0a[off] = 0.f; h0b[off] = 0.f; h1a[off] = 0.f; h1b[off] = 0.f;
  }
}

// Persistent kernel, ONE grid sync per Euler step (flag barrier with embedded deltas).
// Iteration t computes h0(t) [from h0(t-1)] and h1(t-1) [from h0(t-1), h1(t-2)].
__global__ __launch_bounds__(THRv) void k_main(Prm p) {
  const int tid  = threadIdx.x;
  const int bid  = blockIdx.x;
  const int lane = tid & 63;
  const int wv   = tid >> 6;        // wave 0..7 -> j-slice [wv*128, wv*128+128)
  const int lg   = lane & 7;        // b-quad (b = lg*4..lg*4+3)
  const int jq   = lane >> 3;       // j sub-slice 0..7 (16 j each)

  __shared__ __align__(16) float wA [4096];   // Wm0  rows, transposed quads, XOR-swizzled
  __shared__ __align__(16) float wB1[4096];   // Win1 rows
  __shared__ __align__(16) float wBM[4096];   // Wm1  rows
  __shared__ __align__(16) float4 part[64][8];  // [wv*8 + acc][lg]
  __shared__ __align__(16) float  xin_s[4][32];
  __shared__ float bias0[4], bias1[4];
  __shared__ unsigned dmax[2][2];   // [parity][0: d0, 1: d1]

  // ---- stage weights into LDS: slot f4(j) = j ^ ((j>>4)&7) holds quad {w[r=0..3][j]} ----
  {
    const float* A  = p.W_rec;
    const float* M0 = p.mask;
    const float* B1 = p.W_in  + NNv*NNv;
    const float* BM = p.W_rec + NNv*NNv;
    const float* M1 = p.mask  + NNv*NNv;
    const int i0 = bid * 4;
    for (int idx = tid; idx < 4096; idx += THRv) {
      int j = idx & 1023, r = idx >> 10;
      int f = (j ^ ((j >> 4) & 7)) * 4 + r;
      int g = (i0 + r) * NNv + j;
      wA [f] = A [g] * M0[g];
      wB1[f] = B1[g];
      wBM[f] = BM[g] * M1[g];
    }
    if (tid < 128) xin_s[tid >> 5][tid & 31] = p.xin[(i0 + (tid >> 5)) * BSZ + (tid & 31)];
    if (tid < 4) {
      bias0[tid] = p.b_rec[i0 + tid];
      bias1[tid] = p.b_in[NNv + i0 + tid] + p.b_rec[NNv + i0 + tid];
    }
    if (tid == 0) { dmax[0][0] = dmax[0][1] = dmax[1][0] = dmax[1][1] = 0u; }
  }
  __syncthreads();

  const int jb = wv * 128 + jq * 16;           // this thread's j base
  const float4* A4  = ((const float4*)wA ) + jb;
  const float4* B14 = ((const float4*)wB1) + jb;
  const float4* BM4 = ((const float4*)wBM) + jb;

  unsigned prevD0b = 0u;
  int t = 1, K = MAXST;
  for (;;) {
    const int par = t & 1;
    const float4* H0 = (const float4*)(par ? p.h0a : p.h0b);  // h0(t-1)
    const float4* H1 = (const float4*)(par ? p.h1b : p.h1a);  // h1(t-2)
    float* h0w = par ? p.h0b : p.h0a;                         // h0(t)
    float* h1w = par ? p.h1a : p.h1b;                         // h1(t-1)

    // ---- matmul: full-K dot products for this block's 4 rows, both layers ----
    float4 aA0 = {0,0,0,0}, aA1 = aA0, aA2 = aA0, aA3 = aA0;
    float4 aB0 = aA0, aB1v = aA0, aB2 = aA0, aB3 = aA0;
    #pragma unroll
    for (int s = 0; s < 16; ++s) {
      const int j = jb + s;
      const int f = s ^ jq;                 // swizzled quad index (== (j^jq) - jb)
      const float4 h0q = H0[j * 8 + lg];
      const float4 h1q = H1[j * 8 + lg];
      const float4 wa = A4[f], w1 = B14[f], wm = BM4[f];
      fma4(aA0, h0q, wa.x); fma4(aA1, h0q, wa.y); fma4(aA2, h0q, wa.z); fma4(aA3, h0q, wa.w);
      fma4(aB0, h0q, w1.x); fma4(aB1v,h0q, w1.y); fma4(aB2, h0q, w1.z); fma4(aB3, h0q, w1.w);
      fma4(aB0, h1q, wm.x); fma4(aB1v,h1q, wm.y); fma4(aB2, h1q, wm.z); fma4(aB3, h1q, wm.w);
    }
    red4(aA0,8); red4(aA0,16); red4(aA0,32);
    red4(aA1,8); red4(aA1,16); red4(aA1,32);
    red4(aA2,8); red4(aA2,16); red4(aA2,32);
    red4(aA3,8); red4(aA3,16); red4(aA3,32);
    red4(aB0,8); red4(aB0,16); red4(aB0,32);
    red4(aB1v,8); red4(aB1v,16); red4(aB1v,32);
    red4(aB2,8); red4(aB2,16); red4(aB2,32);
    red4(aB3,8); red4(aB3,16); red4(aB3,32);
    if (jq == 0) {
      part[wv*8 + 0][lg] = aA0;  part[wv*8 + 1][lg] = aA1;
      part[wv*8 + 2][lg] = aA2;  part[wv*8 + 3][lg] = aA3;
      part[wv*8 + 4][lg] = aB0;  part[wv*8 + 5][lg] = aB1v;
      part[wv*8 + 6][lg] = aB2;  part[wv*8 + 7][lg] = aB3;
    }
    __syncthreads();

    // ---- epilogue (wave 0): cross-wave sum + sin/update + flag publish ----
    if (wv == 0) {
      const int a = jq;                       // 0..3: layer0 row a; 4..7: layer1 row a-4
      float4 S = part[a][lg];
      #pragma unroll
      for (int w = 1; w < 8; ++w) {
        const float4 q = part[w*8 + a][lg];
        S.x += q.x; S.y += q.y; S.z += q.z; S.w += q.w;
      }
      const int r = a & 3;
      const int i = (bid << 2) + r;
      unsigned d0b = 0u, d1b = 0u;
      if (a < 4) {
        const float4 xs = *((const float4*)&xin_s[r][lg*4]);
        const float  bx = bias0[r];
        const float4 ho = H0[i*8 + lg];
        float4 dh, hn;
        float sx;
        sx = S.x + xs.x + bx; dh.x = fmaf(-ALPHAc, ho.x, sinf(sx)); hn.x = fmaf(dh.x, DTc, ho.x);
        sx = S.y + xs.y + bx; dh.y = fmaf(-ALPHAc, ho.y, sinf(sx)); hn.y = fmaf(dh.y, DTc, ho.y);
        sx = S.z + xs.z + bx; dh.z = fmaf(-ALPHAc, ho.z, sinf(sx)); hn.z = fmaf(dh.z, DTc, ho.z);
        sx = S.w + xs.w + bx; dh.w = fmaf(-ALPHAc, ho.w, sinf(sx)); hn.w = fmaf(dh.w, DTc, ho.w);
        ((float4*)h0w)[i*8 + lg] = hn;
        d0b = amax4bits(dh);
      } else if (t >= 2) {
        const float  bx = bias1[r];
        const float4 ho = H1[i*8 + lg];       // h1(t-2), this block's own rows
        float4 dh, hn;
        float sx;
        sx = S.x + bx; dh.x = fmaf(-ALPHAc, ho.x, sinf(sx)); hn.x = fmaf(dh.x, DTc, ho.x);
        sx = S.y + bx; dh.y = fmaf(-ALPHAc, ho.y, sinf(sx)); hn.y = fmaf(dh.y, DTc, ho.y);
        sx = S.z + bx; dh.z = fmaf(-ALPHAc, ho.z, sinf(sx)); hn.z = fmaf(dh.z, DTc, ho.z);
        sx = S.w + bx; dh.w = fmaf(-ALPHAc, ho.w, sinf(sx)); hn.w = fmaf(dh.w, DTc, ho.w);
        ((float4*)h1w)[i*8 + lg] = hn;
        d1b = amax4bits(dh);
      }
      #pragma unroll
      for (int m = 1; m < 64; m <<= 1) {
        const unsigned o0 = __shfl_xor(d0b, m), o1 = __shfl_xor(d1b, m);
        d0b = d0b > o0 ? d0b : o0;  d1b = d1b > o1 ? d1b : o1;
      }
      if (lane == 0) {
        __threadfence();  // release: h stores -> device-visible before flags
        const u64 tg = (u64)(unsigned)t << 32;
        __hip_atomic_store(p.flag0 + par*GRIDv + bid, tg | (u64)d0b,
                           __ATOMIC_RELAXED, __HIP_MEMORY_SCOPE_AGENT);
        __hip_atomic_store(p.flag1 + par*GRIDv + bid, tg | (u64)d1b,
                           __ATOMIC_RELAXED, __HIP_MEMORY_SCOPE_AGENT);
      }
    }

    // ---- flag barrier: 256 threads poll 256 blocks (both layers) ----
    if (tid < GRIDv) {
      const u64 tag = (u64)(unsigned)t;
      u64 v;
      do { v = __hip_atomic_load(p.flag0 + par*GRIDv + tid,
                                 __ATOMIC_RELAXED, __HIP_MEMORY_SCOPE_AGENT); }
      while ((v >> 32) != tag);
      unsigned m0 = (unsigned)v;
      do { v = __hip_atomic_load(p.flag1 + par*GRIDv + tid,
                                 __ATOMIC_RELAXED, __HIP_MEMORY_SCOPE_AGENT); }
      while ((v >> 32) != tag);
      unsigned m1 = (unsigned)v;
      #pragma unroll
      for (int m = 1; m < 64; m <<= 1) {
        const unsigned o0 = __shfl_xor(m0, m), o1 = __shfl_xor(m1, m);
        m0 = m0 > o0 ? m0 : o0;  m1 = m1 > o1 ? m1 : o1;
      }
      if (lane == 0) { atomicMax(&dmax[par][0], m0); atomicMax(&dmax[par][1], m1); }
    }
    if (tid == THRv - 1) { dmax[par ^ 1][0] = 0u; dmax[par ^ 1][1] = 0u; }  // reset for next iter
    if (wv == 0) __threadfence();   // acquire: invalidate L2 before next step's h reads
    __syncthreads();

    const unsigned D0b = dmax[par][0];   // max|dh0(t)|
    const unsigned D1b = dmax[par][1];   // max|dh1(t-1)|
    if (t >= 2) {
      const unsigned Db = prevD0b > D1b ? prevD0b : D1b;  // D(t-1), NaN-bits sort high
      const float D = __uint_as_float(Db);
      if (!(D >= EPSc) || (t - 1) >= MAXST) { K = t - 1; break; }  // matches JAX cond
    }
    prevD0b = D0b;
    ++t;
  }

  // ---- output: out = h1(K) @ W_out^T + b_out (blocks 0..9, one output column each) ----
  __syncthreads();
  if (bid < NOUTv) {
    const float* h1f = (K & 1) ? p.h1b : p.h1a;
    const int o  = bid;
    const int b  = tid & 31;
    const int ig = tid >> 5;               // 16 i-slices of 64
    float acc = 0.f;
    for (int q = 0; q < 64; ++q) {
      const int i = (ig << 6) + q;
      acc = fmaf(h1f[i*BSZ + b], p.W_out[o*NNv + i], acc);
    }
    float* sr = wA;                        // weights no longer needed
    sr[ig*32 + b] = acc;
    __syncthreads();
    if (tid < 32) {
      float s = p.b_out[o];
      #pragma unroll
      for (int q = 0; q < 16; ++q) s += sr[q*32 + tid];
      p.out[tid*NOUTv + o] = s;            // out[b][o]
    }
  }
}

extern "C" void kernel_launch(void* const* d_in, const int* in_sizes, int n_in,
                              void* d_out, int out_size, void* d_ws, size_t ws_size,
                              hipStream_t stream) {
  const float* X       = (const float*)d_in[0];
  const float* W_input = (const float*)d_in[1];
  const float* b_input = (const float*)d_in[2];
  const float* W_in    = (const float*)d_in[3];
  const float* b_in    = (const float*)d_in[4];
  const float* W_rec   = (const float*)d_in[5];
  const float* mask    = (const float*)d_in[6];
  const float* b_rec   = (const float*)d_in[7];
  const float* W_out   = (const float*)d_in[8];
  const float* b_out   = (const float*)d_in[9];
  (void)in_sizes; (void)n_in; (void)out_size; (void)ws_size;

  float* ws = (float*)d_ws;
  Prm p;
  p.W_in  = W_in;  p.b_in  = b_in;  p.W_rec = W_rec; p.mask = mask;
  p.b_rec = b_rec; p.W_out = W_out; p.b_out = b_out;
  p.xin = ws + WS_XIN;
  p.h0a = ws + WS_H0A; p.h0b = ws + WS_H0B;
  p.h1a = ws + WS_H1A; p.h1b = ws + WS_H1B;
  p.flag0 = (u64*)(ws + WS_FLG);
  p.flag1 = p.flag0 + 2 * GRIDv;
  p.out  = (float*)d_out;

  k_xin<<<NNv, 256, 0, stream>>>(X, W_input, b_input,
                                 (float*)p.xin, p.h0a, p.h0b, p.h1a, p.h1b);
  k_main<<<GRIDv, THRv, 0, stream>>>(p);
}

// Round 8
// 4181.973 us; speedup vs baseline: 2.0878x; 1.1561x over previous
//
#include <hip/hip_runtime.h>
#include <math.h>

// ---------------- problem constants ----------------
#define NNv    1024
#define BSZ    32
#define NINv   784
#define NOUTv  10
#define ALPHAc 0.9f
#define DTc    0.05f
#define EPSc   0.05f
#define MAXST  1000

// ---------------- launch geometry ----------------
#define GRIDv  256      // 1 block per CU; each block owns 4 rows of both layers
#define THRv   512      // 8 waves

// ---------------- workspace layout (float indices) ----------------
#define WS_XIN 0
#define WS_H0A 32768
#define WS_H0B 65536
#define WS_H1A 98304
#define WS_H1B 131072
#define WS_FLG 163840   // flag0[2][256] u64, then flag1[2][256] u64

typedef unsigned long long u64;
typedef float f4v __attribute__((ext_vector_type(4)));

struct Prm {
  const float *W_in, *b_in, *W_rec, *mask, *b_rec, *W_out, *b_out, *xin;
  float *h0a, *h0b, *h1a, *h1b, *out;
  u64 *flag0, *flag1;
};

__device__ __forceinline__ void fma4(f4v& a, const f4v h, const float w) {
  a.x = fmaf(h.x, w, a.x); a.y = fmaf(h.y, w, a.y);
  a.z = fmaf(h.z, w, a.z); a.w = fmaf(h.w, w, a.w);
}
__device__ __forceinline__ void red4(f4v& a, int m) {
  a.x += __shfl_xor(a.x, m); a.y += __shfl_xor(a.y, m);
  a.z += __shfl_xor(a.z, m); a.w += __shfl_xor(a.w, m);
}
__device__ __forceinline__ unsigned amax4bits(const f4v d) {
  float m = fmaxf(fmaxf(fabsf(d.x), fabsf(d.y)), fmaxf(fabsf(d.z), fabsf(d.w)));
  return __float_as_uint(m);   // fabs => bit31 clear; uint compare == float compare
}

// coherent (MALL-fresh, L1/L2-bypass) 16B load, embedded wait
__device__ __forceinline__ f4v ldg4_sc(const f4v* p) {
  f4v r;
  asm volatile("global_load_dwordx4 %0, %1, off sc0 sc1\n\t"
               "s_waitcnt vmcnt(0)"
               : "=&v"(r) : "v"(p) : "memory");
  return r;
}

// x_in = X @ W_input^T + b_input, stored [i][b]; zero all four h state buffers
__global__ __launch_bounds__(256) void k_xin(const float* X, const float* Wi, const float* bi,
                                             float* xin, float* h0a, float* h0b,
                                             float* h1a, float* h1b) {
  int i  = blockIdx.x;
  int b  = threadIdx.x & 31;
  int fs = threadIdx.x >> 5;
  const float* xr = X  + b * NINv;
  const float* wr = Wi + i * NINv;
  float acc = 0.f;
  for (int f = fs; f < NINv; f += 8) acc = fmaf(xr[f], wr[f], acc);
  __shared__ float red[8][32];
  red[fs][b] = acc;
  __syncthreads();
  if (threadIdx.x < 32) {
    float s = bi[i];
    #pragma unroll
    for (int q = 0; q < 8; ++q) s += red[q][threadIdx.x];
    int off = i * BSZ + threadIdx.x;
    xin[off] = s;
    h0a[off] = 0.f; h0b[off] = 0.f; h1a[off] = 0.f; h1b[off] = 0.f;
  }
}

// Persistent kernel, ONE grid sync per Euler step.
// Release: plain h stores + __threadfence() (round-2-verified) before flag publish.
// Acquire: NONE — all cross-block reads (flags, h state) are L1/L2-bypassing
// (sc0 sc1 / agent-scope atomics), so they read the coherence point directly.
// Iteration t computes h0(t) [from h0(t-1)] and h1(t-1) [from h0(t-1), h1(t-2)].
__global__ __launch_bounds__(THRv) void k_main(Prm p) {
  const int tid  = threadIdx.x;
  const int bid  = blockIdx.x;
  const int lane = tid & 63;
  const int wv   = tid >> 6;        // wave 0..7 -> j-slice [wv*128, wv*128+128)
  const int lg   = lane & 7;        // b-quad (b = lg*4..lg*4+3)
  const int jq   = lane >> 3;       // j sub-slice 0..7 (16 j each)

  __shared__ __align__(16) float wA [4096];   // Wm0  rows, transposed quads, XOR-swizzled
  __shared__ __align__(16) float wB1[4096];   // Win1 rows
  __shared__ __align__(16) float wBM[4096];   // Wm1  rows
  __shared__ __align__(16) f4v  part[64][8];  // [wv*8 + acc][lg]
  __shared__ __align__(16) float xin_s[4][32];
  __shared__ float bias0[4], bias1[4];
  __shared__ unsigned dmax[2][2];   // [parity][0: d0, 1: d1]

  // ---- stage weights into LDS: slot f4(j) = j ^ ((j>>4)&7) holds quad {w[r=0..3][j]} ----
  {
    const float* A  = p.W_rec;
    const float* M0 = p.mask;
    const float* B1 = p.W_in  + NNv*NNv;
    const float* BM = p.W_rec + NNv*NNv;
    const float* M1 = p.mask  + NNv*NNv;
    const int i0 = bid * 4;
    for (int idx = tid; idx < 4096; idx += THRv) {
      int j = idx & 1023, r = idx >> 10;
      int f = (j ^ ((j >> 4) & 7)) * 4 + r;
      int g = (i0 + r) * NNv + j;
      wA [f] = A [g] * M0[g];
      wB1[f] = B1[g];
      wBM[f] = BM[g] * M1[g];
    }
    if (tid < 128) xin_s[tid >> 5][tid & 31] = p.xin[(i0 + (tid >> 5)) * BSZ + (tid & 31)];
    if (tid < 4) {
      bias0[tid] = p.b_rec[i0 + tid];
      bias1[tid] = p.b_in[NNv + i0 + tid] + p.b_rec[NNv + i0 + tid];
    }
    if (tid == 0) { dmax[0][0] = dmax[0][1] = dmax[1][0] = dmax[1][1] = 0u; }
  }
  __syncthreads();

  const int jb = wv * 128 + jq * 16;           // this thread's j base (16 quads)
  const f4v* A4  = ((const f4v*)wA );
  const f4v* B14 = ((const f4v*)wB1);
  const f4v* BM4 = ((const f4v*)wBM);

  unsigned prevD0b = 0u;
  int t = 1, K = MAXST;
  for (;;) {
    const int par = t & 1;
    const f4v* H0 = (const f4v*)(par ? p.h0a : p.h0b);  // h0(t-1)
    const f4v* H1 = (const f4v*)(par ? p.h1b : p.h1a);  // h1(t-2)
    float* h0w = par ? p.h0b : p.h0a;                   // h0(t)
    float* h1w = par ? p.h1a : p.h1b;                   // h1(t-1)

    // ---- matmul: full-K dots for this block's 4 rows, both layers; batched sc loads ----
    f4v aA0 = {0,0,0,0}, aA1 = aA0, aA2 = aA0, aA3 = aA0;
    f4v aB0 = aA0, aB1v = aA0, aB2 = aA0, aB3 = aA0;
    #pragma unroll
    for (int c = 0; c < 2; ++c) {
      const f4v* P0 = H0 + (jb + c*8)*8 + lg;
      const f4v* P1 = H1 + (jb + c*8)*8 + lg;
      f4v h0q0,h0q1,h0q2,h0q3,h0q4,h0q5,h0q6,h0q7;
      f4v h1q0,h1q1,h1q2,h1q3,h1q4,h1q5,h1q6,h1q7;
      asm volatile(
        "global_load_dwordx4 %0, %16, off sc0 sc1\n\t"
        "global_load_dwordx4 %1, %16, off offset:128 sc0 sc1\n\t"
        "global_load_dwordx4 %2, %16, off offset:256 sc0 sc1\n\t"
        "global_load_dwordx4 %3, %16, off offset:384 sc0 sc1\n\t"
        "global_load_dwordx4 %4, %16, off offset:512 sc0 sc1\n\t"
        "global_load_dwordx4 %5, %16, off offset:640 sc0 sc1\n\t"
        "global_load_dwordx4 %6, %16, off offset:768 sc0 sc1\n\t"
        "global_load_dwordx4 %7, %16, off offset:896 sc0 sc1\n\t"
        "global_load_dwordx4 %8, %17, off sc0 sc1\n\t"
        "global_load_dwordx4 %9, %17, off offset:128 sc0 sc1\n\t"
        "global_load_dwordx4 %10, %17, off offset:256 sc0 sc1\n\t"
        "global_load_dwordx4 %11, %17, off offset:384 sc0 sc1\n\t"
        "global_load_dwordx4 %12, %17, off offset:512 sc0 sc1\n\t"
        "global_load_dwordx4 %13, %17, off offset:640 sc0 sc1\n\t"
        "global_load_dwordx4 %14, %17, off offset:768 sc0 sc1\n\t"
        "global_load_dwordx4 %15, %17, off offset:896 sc0 sc1\n\t"
        "s_waitcnt vmcnt(0)"
        : "=&v"(h0q0),"=&v"(h0q1),"=&v"(h0q2),"=&v"(h0q3),
          "=&v"(h0q4),"=&v"(h0q5),"=&v"(h0q6),"=&v"(h0q7),
          "=&v"(h1q0),"=&v"(h1q1),"=&v"(h1q2),"=&v"(h1q3),
          "=&v"(h1q4),"=&v"(h1q5),"=&v"(h1q6),"=&v"(h1q7)
        : "v"(P0), "v"(P1)
        : "memory");
      __builtin_amdgcn_sched_barrier(0);
      const int cb = jb + c * 8;     // LDS quad window base for this c-chunk
      #define MMSTEP(H0Q, H1Q, S2) { \
        const int f_ = cb + ((S2) ^ jq); \
        const f4v wa = A4[f_], w1 = B14[f_], wm = BM4[f_]; \
        fma4(aA0, H0Q, wa.x); fma4(aA1, H0Q, wa.y); fma4(aA2, H0Q, wa.z); fma4(aA3, H0Q, wa.w); \
        fma4(aB0, H0Q, w1.x); fma4(aB1v,H0Q, w1.y); fma4(aB2, H0Q, w1.z); fma4(aB3, H0Q, w1.w); \
        fma4(aB0, H1Q, wm.x); fma4(aB1v,H1Q, wm.y); fma4(aB2, H1Q, wm.z); fma4(aB3, H1Q, wm.w); }
      MMSTEP(h0q0, h1q0, 0)  MMSTEP(h0q1, h1q1, 1)
      MMSTEP(h0q2, h1q2, 2)  MMSTEP(h0q3, h1q3, 3)
      MMSTEP(h0q4, h1q4, 4)  MMSTEP(h0q5, h1q5, 5)
      MMSTEP(h0q6, h1q6, 6)  MMSTEP(h0q7, h1q7, 7)
      #undef MMSTEP
    }
    red4(aA0,8); red4(aA0,16); red4(aA0,32);
    red4(aA1,8); red4(aA1,16); red4(aA1,32);
    red4(aA2,8); red4(aA2,16); red4(aA2,32);
    red4(aA3,8); red4(aA3,16); red4(aA3,32);
    red4(aB0,8); red4(aB0,16); red4(aB0,32);
    red4(aB1v,8); red4(aB1v,16); red4(aB1v,32);
    red4(aB2,8); red4(aB2,16); red4(aB2,32);
    red4(aB3,8); red4(aB3,16); red4(aB3,32);
    if (jq == 0) {
      part[wv*8 + 0][lg] = aA0;  part[wv*8 + 1][lg] = aA1;
      part[wv*8 + 2][lg] = aA2;  part[wv*8 + 3][lg] = aA3;
      part[wv*8 + 4][lg] = aB0;  part[wv*8 + 5][lg] = aB1v;
      part[wv*8 + 6][lg] = aB2;  part[wv*8 + 7][lg] = aB3;
    }
    __syncthreads();

    // ---- epilogue (wave 0): cross-wave sum + sin/update + plain h store + fence + flag ----
    if (wv == 0) {
      const int a = jq;                       // 0..3: layer0 row a; 4..7: layer1 row a-4
      f4v S = part[a][lg];
      #pragma unroll
      for (int w = 1; w < 8; ++w) {
        const f4v q = part[w*8 + a][lg];
        S.x += q.x; S.y += q.y; S.z += q.z; S.w += q.w;
      }
      const int r = a & 3;
      const int i = (bid << 2) + r;
      unsigned d0b = 0u, d1b = 0u;
      if (a < 4) {
        const f4v  xs = *((const f4v*)&xin_s[r][lg*4]);
        const float bx = bias0[r];
        const f4v  ho = ldg4_sc(&H0[i*8 + lg]);
        f4v dh, hn;
        float sx;
        sx = S.x + xs.x + bx; dh.x = fmaf(-ALPHAc, ho.x, sinf(sx)); hn.x = fmaf(dh.x, DTc, ho.x);
        sx = S.y + xs.y + bx; dh.y = fmaf(-ALPHAc, ho.y, sinf(sx)); hn.y = fmaf(dh.y, DTc, ho.y);
        sx = S.z + xs.z + bx; dh.z = fmaf(-ALPHAc, ho.z, sinf(sx)); hn.z = fmaf(dh.z, DTc, ho.z);
        sx = S.w + xs.w + bx; dh.w = fmaf(-ALPHAc, ho.w, sinf(sx)); hn.w = fmaf(dh.w, DTc, ho.w);
        ((f4v*)h0w)[i*8 + lg] = hn;            // plain store; fence below publishes
        d0b = amax4bits(dh);
      } else if (t >= 2) {
        const float bx = bias1[r];
        const f4v  ho = ldg4_sc(&H1[i*8 + lg]);     // h1(t-2), this block's own rows
        f4v dh, hn;
        float sx;
        sx = S.x + bx; dh.x = fmaf(-ALPHAc, ho.x, sinf(sx)); hn.x = fmaf(dh.x, DTc, ho.x);
        sx = S.y + bx; dh.y = fmaf(-ALPHAc, ho.y, sinf(sx)); hn.y = fmaf(dh.y, DTc, ho.y);
        sx = S.z + bx; dh.z = fmaf(-ALPHAc, ho.z, sinf(sx)); hn.z = fmaf(dh.z, DTc, ho.z);
        sx = S.w + bx; dh.w = fmaf(-ALPHAc, ho.w, sinf(sx)); hn.w = fmaf(dh.w, DTc, ho.w);
        ((f4v*)h1w)[i*8 + lg] = hn;            // plain store; fence below publishes
        d1b = amax4bits(dh);
      }
      #pragma unroll
      for (int m = 1; m < 64; m <<= 1) {
        const unsigned o0 = __shfl_xor(d0b, m), o1 = __shfl_xor(d1b, m);
        d0b = d0b > o0 ? d0b : o0;  d1b = d1b > o1 ? d1b : o1;
      }
      if (lane == 0) {
        __threadfence();  // RELEASE (verified in round 2): h stores -> coherence point
        const u64 tg = (u64)(unsigned)t << 32;
        __hip_atomic_store(p.flag0 + par*GRIDv + bid, tg | (u64)d0b,
                           __ATOMIC_RELAXED, __HIP_MEMORY_SCOPE_AGENT);
        __hip_atomic_store(p.flag1 + par*GRIDv + bid, tg | (u64)d1b,
                           __ATOMIC_RELAXED, __HIP_MEMORY_SCOPE_AGENT);
      }
    }

    // ---- flag barrier: 256 threads poll 256 blocks; NO acquire fence needed ----
    if (tid < GRIDv) {
      const u64 tag = (u64)(unsigned)t;
      u64 v;
      do { v = __hip_atomic_load(p.flag0 + par*GRIDv + tid,
                                 __ATOMIC_RELAXED, __HIP_MEMORY_SCOPE_AGENT); }
      while ((v >> 32) != tag);
      unsigned m0 = (unsigned)v;
      do { v = __hip_atomic_load(p.flag1 + par*GRIDv + tid,
                                 __ATOMIC_RELAXED, __HIP_MEMORY_SCOPE_AGENT); }
      while ((v >> 32) != tag);
      unsigned m1 = (unsigned)v;
      #pragma unroll
      for (int m = 1; m < 64; m <<= 1) {
        const unsigned o0 = __shfl_xor(m0, m), o1 = __shfl_xor(m1, m);
        m0 = m0 > o0 ? m0 : o0;  m1 = m1 > o1 ? m1 : o1;
      }
      if (lane == 0) { atomicMax(&dmax[par][0], m0); atomicMax(&dmax[par][1], m1); }
    }
    if (tid == THRv - 1) { dmax[par ^ 1][0] = 0u; dmax[par ^ 1][1] = 0u; }  // reset for next iter
    __syncthreads();

    const unsigned D0b = dmax[par][0];   // max|dh0(t)|
    const unsigned D1b = dmax[par][1];   // max|dh1(t-1)|
    if (t >= 2) {
      const unsigned Db = prevD0b > D1b ? prevD0b : D1b;  // D(t-1), NaN-bits sort high
      const float D = __uint_as_float(Db);
      if (!(D >= EPSc) || (t - 1) >= MAXST) { K = t - 1; break; }  // matches JAX cond
    }
    prevD0b = D0b;
    ++t;
  }

  // ---- output: out = h1(K) @ W_out^T + b_out (blocks 0..9, one output column each) ----
  __syncthreads();
  if (bid < NOUTv) {
    const float* h1f = (K & 1) ? p.h1b : p.h1a;
    const int o  = bid;
    const int b  = tid & 31;
    const int ig = tid >> 5;               // 16 i-slices of 64
    const float* wrow = p.W_out + o * NNv;
    float acc = 0.f;
    for (int qq = 0; qq < 8; ++qq) {
      const int i0 = (ig << 6) + qq * 8;
      const float* q0 = h1f + i0 * BSZ + b;
      float v0,v1,v2,v3,v4,v5,v6,v7;
      asm volatile(
        "global_load_dword %0, %8, off sc0 sc1\n\t"
        "global_load_dword %1, %8, off offset:128 sc0 sc1\n\t"
        "global_load_dword %2, %8, off offset:256 sc0 sc1\n\t"
        "global_load_dword %3, %8, off offset:384 sc0 sc1\n\t"
        "global_load_dword %4, %8, off offset:512 sc0 sc1\n\t"
        "global_load_dword %5, %8, off offset:640 sc0 sc1\n\t"
        "global_load_dword %6, %8, off offset:768 sc0 sc1\n\t"
        "global_load_dword %7, %8, off offset:896 sc0 sc1\n\t"
        "s_waitcnt vmcnt(0)"
        : "=&v"(v0),"=&v"(v1),"=&v"(v2),"=&v"(v3),
          "=&v"(v4),"=&v"(v5),"=&v"(v6),"=&v"(v7)
        : "v"(q0) : "memory");
      acc = fmaf(v0, wrow[i0+0], acc);
      acc = fmaf(v1, wrow[i0+1], acc);
      acc = fmaf(v2, wrow[i0+2], acc);
      acc = fmaf(v3, wrow[i0+3], acc);
      acc = fmaf(v4, wrow[i0+4], acc);
      acc = fmaf(v5, wrow[i0+5], acc);
      acc = fmaf(v6, wrow[i0+6], acc);
      acc = fmaf(v7, wrow[i0+7], acc);
    }
    float* sr = wA;                        // weights no longer needed
    sr[ig*32 + b] = acc;
    __syncthreads();
    if (tid < 32) {
      float s = p.b_out[o];
      #pragma unroll
      for (int q = 0; q < 16; ++q) s += sr[q*32 + tid];
      p.out[tid*NOUTv + o] = s;            // out[b][o]
    }
  }
}

extern "C" void kernel_launch(void* const* d_in, const int* in_sizes, int n_in,
                              void* d_out, int out_size, void* d_ws, size_t ws_size,
                              hipStream_t stream) {
  const float* X       = (const float*)d_in[0];
  const float* W_input = (const float*)d_in[1];
  const float* b_input = (const float*)d_in[2];
  const float* W_in    = (const float*)d_in[3];
  const float* b_in    = (const float*)d_in[4];
  const float* W_rec   = (const float*)d_in[5];
  const float* mask    = (const float*)d_in[6];
  const float* b_rec   = (const float*)d_in[7];
  const float* W_out   = (const float*)d_in[8];
  const float* b_out   = (const float*)d_in[9];
  (void)in_sizes; (void)n_in; (void)out_size; (void)ws_size;

  float* ws = (float*)d_ws;
  Prm p;
  p.W_in  = W_in;  p.b_in  = b_in;  p.W_rec = W_rec; p.mask = mask;
  p.b_rec = b_rec; p.W_out = W_out; p.b_out = b_out;
  p.xin = ws + WS_XIN;
  p.h0a = ws + WS_H0A; p.h0b = ws + WS_H0B;
  p.h1a = ws + WS_H1A; p.h1b = ws + WS_H1B;
  p.flag0 = (u64*)(ws + WS_FLG);
  p.flag1 = p.flag0 + 2 * GRIDv;
  p.out  = (float*)d_out;

  k_xin<<<NNv, 256, 0, stream>>>(X, W_input, b_input,
                                 (float*)p.xin, p.h0a, p.h0b, p.h1a, p.h1b);
  k_main<<<GRIDv, THRv, 0, stream>>>(p);
}

// Round 9
// 3045.360 us; speedup vs baseline: 2.8671x; 1.3732x over previous
//
#include <hip/hip_runtime.h>
#include <math.h>

// ---------------- problem constants ----------------
#define NNv    1024
#define BSZ    32
#define NINv   784
#define NOUTv  10
#define ALPHAc 0.9f
#define DTc    0.05f
#define EPSc   0.05f
#define MAXST  1000

// ---------------- launch geometry ----------------
#define GRIDv  256      // 1 block per CU; each block owns 4 rows of both layers
#define THRv   512      // 8 waves

// ---------------- workspace layout (float indices) ----------------
#define WS_XIN 0
#define WS_H0A 32768
#define WS_H0B 65536
#define WS_H1A 98304
#define WS_H1B 131072
#define WS_FLG 163840   // flag0[2][256] u64, then flag1[2][256] u64

typedef unsigned long long u64;
typedef float f4v __attribute__((ext_vector_type(4)));

struct Prm {
  const float *W_in, *b_in, *W_rec, *mask, *b_rec, *W_out, *b_out, *xin;
  float *h0a, *h0b, *h1a, *h1b, *out;
  u64 *flag0, *flag1;
};

__device__ __forceinline__ void fma4(f4v& a, const f4v h, const float w) {
  a.x = fmaf(h.x, w, a.x); a.y = fmaf(h.y, w, a.y);
  a.z = fmaf(h.z, w, a.z); a.w = fmaf(h.w, w, a.w);
}
__device__ __forceinline__ void red4(f4v& a, int m) {
  a.x += __shfl_xor(a.x, m); a.y += __shfl_xor(a.y, m);
  a.z += __shfl_xor(a.z, m); a.w += __shfl_xor(a.w, m);
}
__device__ __forceinline__ unsigned amax4bits(const f4v d) {
  float m = fmaxf(fmaxf(fabsf(d.x), fabsf(d.y)), fmaxf(fabsf(d.z), fabsf(d.w)));
  return __float_as_uint(m);   // fabs => bit31 clear; uint compare == float compare
}

// coherent (MALL-fresh, L1/L2-bypass) 16B load, embedded wait
__device__ __forceinline__ f4v ldg4_sc(const f4v* p) {
  f4v r;
  asm volatile("global_load_dwordx4 %0, %1, off sc0 sc1\n\t"
               "s_waitcnt vmcnt(0)"
               : "=&v"(r) : "v"(p) : "memory");
  return r;
}

// far-atomic 16B store: two u64 swaps execute AT the coherence point (MALL).
// Returning form (sc0): when vmcnt drains, the data is PROVABLY at MALL —
// unlike a write-through store, whose vmcnt-ack precedes L2->MALL completion.
__device__ __forceinline__ void stg16_far(f4v* p, const f4v v) {
  u64 d0 = ((u64)__float_as_uint(v.y) << 32) | (u64)__float_as_uint(v.x);
  u64 d1 = ((u64)__float_as_uint(v.w) << 32) | (u64)__float_as_uint(v.z);
  u64 o0, o1;
  asm volatile(
    "global_atomic_swap_x2 %0, %2, %3, off sc0 sc1\n\t"
    "global_atomic_swap_x2 %1, %4, %5, off sc0 sc1"
    : "=&v"(o0), "=&v"(o1)
    : "v"(p), "v"(d0), "v"((char*)p + 8), "v"(d1)
    : "memory");
  asm volatile("" :: "v"(o0), "v"(o1));  // keep returned olds live
}

// x_in = X @ W_input^T + b_input, stored [i][b]; zero all four h state buffers
__global__ __launch_bounds__(256) void k_xin(const float* X, const float* Wi, const float* bi,
                                             float* xin, float* h0a, float* h0b,
                                             float* h1a, float* h1b) {
  int i  = blockIdx.x;
  int b  = threadIdx.x & 31;
  int fs = threadIdx.x >> 5;
  const float* xr = X  + b * NINv;
  const float* wr = Wi + i * NINv;
  float acc = 0.f;
  for (int f = fs; f < NINv; f += 8) acc = fmaf(xr[f], wr[f], acc);
  __shared__ float red[8][32];
  red[fs][b] = acc;
  __syncthreads();
  if (threadIdx.x < 32) {
    float s = bi[i];
    #pragma unroll
    for (int q = 0; q < 8; ++q) s += red[q][threadIdx.x];
    int off = i * BSZ + threadIdx.x;
    xin[off] = s;
    h0a[off] = 0.f; h0b[off] = 0.f; h1a[off] = 0.f; h1b[off] = 0.f;
  }
}

// Persistent kernel, ONE grid sync per Euler step, ZERO cache-maintenance ops.
// Release: h stored via far atomics (at MALL) + s_waitcnt vmcnt(0) + flag store.
// Acquire: none — all cross-block reads (flags, h) are L1/L2-bypassing.
// Iteration t computes h0(t) [from h0(t-1)] and h1(t-1) [from h0(t-1), h1(t-2)].
__global__ __launch_bounds__(THRv) void k_main(Prm p) {
  const int tid  = threadIdx.x;
  const int bid  = blockIdx.x;
  const int lane = tid & 63;
  const int wv   = tid >> 6;        // wave 0..7 -> j-slice [wv*128, wv*128+128)
  const int lg   = lane & 7;        // b-quad (b = lg*4..lg*4+3)
  const int jq   = lane >> 3;       // j sub-slice 0..7 (16 j each)

  __shared__ __align__(16) float wA [4096];   // Wm0  rows, transposed quads, XOR-swizzled
  __shared__ __align__(16) float wB1[4096];   // Win1 rows
  __shared__ __align__(16) float wBM[4096];   // Wm1  rows
  __shared__ __align__(16) f4v  part[64][8];  // [wv*8 + acc][lg]
  __shared__ __align__(16) float xin_s[4][32];
  __shared__ float bias0[4], bias1[4];
  __shared__ unsigned dmax[2][2];   // [parity][0: d0, 1: d1]

  // ---- stage weights into LDS: slot f4(j) = j ^ ((j>>4)&7) holds quad {w[r=0..3][j]} ----
  {
    const float* A  = p.W_rec;
    const float* M0 = p.mask;
    const float* B1 = p.W_in  + NNv*NNv;
    const float* BM = p.W_rec + NNv*NNv;
    const float* M1 = p.mask  + NNv*NNv;
    const int i0 = bid * 4;
    for (int idx = tid; idx < 4096; idx += THRv) {
      int j = idx & 1023, r = idx >> 10;
      int f = (j ^ ((j >> 4) & 7)) * 4 + r;
      int g = (i0 + r) * NNv + j;
      wA [f] = A [g] * M0[g];
      wB1[f] = B1[g];
      wBM[f] = BM[g] * M1[g];
    }
    if (tid < 128) xin_s[tid >> 5][tid & 31] = p.xin[(i0 + (tid >> 5)) * BSZ + (tid & 31)];
    if (tid < 4) {
      bias0[tid] = p.b_rec[i0 + tid];
      bias1[tid] = p.b_in[NNv + i0 + tid] + p.b_rec[NNv + i0 + tid];
    }
    if (tid == 0) { dmax[0][0] = dmax[0][1] = dmax[1][0] = dmax[1][1] = 0u; }
  }
  __syncthreads();

  const int jb = wv * 128 + jq * 16;           // this thread's j base (16 quads)
  const f4v* A4  = ((const f4v*)wA );
  const f4v* B14 = ((const f4v*)wB1);
  const f4v* BM4 = ((const f4v*)wBM);

  unsigned prevD0b = 0u;
  int t = 1, K = MAXST;
  for (;;) {
    const int par = t & 1;
    const f4v* H0 = (const f4v*)(par ? p.h0a : p.h0b);  // h0(t-1)
    const f4v* H1 = (const f4v*)(par ? p.h1b : p.h1a);  // h1(t-2)
    float* h0w = par ? p.h0b : p.h0a;                   // h0(t)
    float* h1w = par ? p.h1a : p.h1b;                   // h1(t-1)

    // ---- matmul: full-K dots for this block's 4 rows, both layers; batched sc loads ----
    f4v aA0 = {0,0,0,0}, aA1 = aA0, aA2 = aA0, aA3 = aA0;
    f4v aB0 = aA0, aB1v = aA0, aB2 = aA0, aB3 = aA0;
    #pragma unroll
    for (int c = 0; c < 2; ++c) {
      const f4v* P0 = H0 + (jb + c*8)*8 + lg;
      const f4v* P1 = H1 + (jb + c*8)*8 + lg;
      f4v h0q0,h0q1,h0q2,h0q3,h0q4,h0q5,h0q6,h0q7;
      f4v h1q0,h1q1,h1q2,h1q3,h1q4,h1q5,h1q6,h1q7;
      asm volatile(
        "global_load_dwordx4 %0, %16, off sc0 sc1\n\t"
        "global_load_dwordx4 %1, %16, off offset:128 sc0 sc1\n\t"
        "global_load_dwordx4 %2, %16, off offset:256 sc0 sc1\n\t"
        "global_load_dwordx4 %3, %16, off offset:384 sc0 sc1\n\t"
        "global_load_dwordx4 %4, %16, off offset:512 sc0 sc1\n\t"
        "global_load_dwordx4 %5, %16, off offset:640 sc0 sc1\n\t"
        "global_load_dwordx4 %6, %16, off offset:768 sc0 sc1\n\t"
        "global_load_dwordx4 %7, %16, off offset:896 sc0 sc1\n\t"
        "global_load_dwordx4 %8, %17, off sc0 sc1\n\t"
        "global_load_dwordx4 %9, %17, off offset:128 sc0 sc1\n\t"
        "global_load_dwordx4 %10, %17, off offset:256 sc0 sc1\n\t"
        "global_load_dwordx4 %11, %17, off offset:384 sc0 sc1\n\t"
        "global_load_dwordx4 %12, %17, off offset:512 sc0 sc1\n\t"
        "global_load_dwordx4 %13, %17, off offset:640 sc0 sc1\n\t"
        "global_load_dwordx4 %14, %17, off offset:768 sc0 sc1\n\t"
        "global_load_dwordx4 %15, %17, off offset:896 sc0 sc1\n\t"
        "s_waitcnt vmcnt(0)"
        : "=&v"(h0q0),"=&v"(h0q1),"=&v"(h0q2),"=&v"(h0q3),
          "=&v"(h0q4),"=&v"(h0q5),"=&v"(h0q6),"=&v"(h0q7),
          "=&v"(h1q0),"=&v"(h1q1),"=&v"(h1q2),"=&v"(h1q3),
          "=&v"(h1q4),"=&v"(h1q5),"=&v"(h1q6),"=&v"(h1q7)
        : "v"(P0), "v"(P1)
        : "memory");
      __builtin_amdgcn_sched_barrier(0);
      const int cb = jb + c * 8;     // LDS quad window base for this c-chunk
      #define MMSTEP(H0Q, H1Q, S2) { \
        const int f_ = cb + ((S2) ^ jq); \
        const f4v wa = A4[f_], w1 = B14[f_], wm = BM4[f_]; \
        fma4(aA0, H0Q, wa.x); fma4(aA1, H0Q, wa.y); fma4(aA2, H0Q, wa.z); fma4(aA3, H0Q, wa.w); \
        fma4(aB0, H0Q, w1.x); fma4(aB1v,H0Q, w1.y); fma4(aB2, H0Q, w1.z); fma4(aB3, H0Q, w1.w); \
        fma4(aB0, H1Q, wm.x); fma4(aB1v,H1Q, wm.y); fma4(aB2, H1Q, wm.z); fma4(aB3, H1Q, wm.w); }
      MMSTEP(h0q0, h1q0, 0)  MMSTEP(h0q1, h1q1, 1)
      MMSTEP(h0q2, h1q2, 2)  MMSTEP(h0q3, h1q3, 3)
      MMSTEP(h0q4, h1q4, 4)  MMSTEP(h0q5, h1q5, 5)
      MMSTEP(h0q6, h1q6, 6)  MMSTEP(h0q7, h1q7, 7)
      #undef MMSTEP
    }
    red4(aA0,8); red4(aA0,16); red4(aA0,32);
    red4(aA1,8); red4(aA1,16); red4(aA1,32);
    red4(aA2,8); red4(aA2,16); red4(aA2,32);
    red4(aA3,8); red4(aA3,16); red4(aA3,32);
    red4(aB0,8); red4(aB0,16); red4(aB0,32);
    red4(aB1v,8); red4(aB1v,16); red4(aB1v,32);
    red4(aB2,8); red4(aB2,16); red4(aB2,32);
    red4(aB3,8); red4(aB3,16); red4(aB3,32);
    if (jq == 0) {
      part[wv*8 + 0][lg] = aA0;  part[wv*8 + 1][lg] = aA1;
      part[wv*8 + 2][lg] = aA2;  part[wv*8 + 3][lg] = aA3;
      part[wv*8 + 4][lg] = aB0;  part[wv*8 + 5][lg] = aB1v;
      part[wv*8 + 6][lg] = aB2;  part[wv*8 + 7][lg] = aB3;
    }
    __syncthreads();

    // ---- epilogue (wave 0): cross-wave sum + sin/update + far-atomic h store + flag ----
    if (wv == 0) {
      const int a = jq;                       // 0..3: layer0 row a; 4..7: layer1 row a-4
      f4v S = part[a][lg];
      #pragma unroll
      for (int w = 1; w < 8; ++w) {
        const f4v q = part[w*8 + a][lg];
        S.x += q.x; S.y += q.y; S.z += q.z; S.w += q.w;
      }
      const int r = a & 3;
      const int i = (bid << 2) + r;
      unsigned d0b = 0u, d1b = 0u;
      if (a < 4) {
        const f4v  xs = *((const f4v*)&xin_s[r][lg*4]);
        const float bx = bias0[r];
        const f4v  ho = ldg4_sc(&H0[i*8 + lg]);
        f4v dh, hn;
        float sx;
        sx = S.x + xs.x + bx; dh.x = fmaf(-ALPHAc, ho.x, sinf(sx)); hn.x = fmaf(dh.x, DTc, ho.x);
        sx = S.y + xs.y + bx; dh.y = fmaf(-ALPHAc, ho.y, sinf(sx)); hn.y = fmaf(dh.y, DTc, ho.y);
        sx = S.z + xs.z + bx; dh.z = fmaf(-ALPHAc, ho.z, sinf(sx)); hn.z = fmaf(dh.z, DTc, ho.z);
        sx = S.w + xs.w + bx; dh.w = fmaf(-ALPHAc, ho.w, sinf(sx)); hn.w = fmaf(dh.w, DTc, ho.w);
        stg16_far(((f4v*)h0w) + i*8 + lg, hn);   // lands AT MALL
        d0b = amax4bits(dh);
      } else if (t >= 2) {
        const float bx = bias1[r];
        const f4v  ho = ldg4_sc(&H1[i*8 + lg]);     // h1(t-2), this block's own rows
        f4v dh, hn;
        float sx;
        sx = S.x + bx; dh.x = fmaf(-ALPHAc, ho.x, sinf(sx)); hn.x = fmaf(dh.x, DTc, ho.x);
        sx = S.y + bx; dh.y = fmaf(-ALPHAc, ho.y, sinf(sx)); hn.y = fmaf(dh.y, DTc, ho.y);
        sx = S.z + bx; dh.z = fmaf(-ALPHAc, ho.z, sinf(sx)); hn.z = fmaf(dh.z, DTc, ho.z);
        sx = S.w + bx; dh.w = fmaf(-ALPHAc, ho.w, sinf(sx)); hn.w = fmaf(dh.w, DTc, ho.w);
        stg16_far(((f4v*)h1w) + i*8 + lg, hn);   // lands AT MALL
        d1b = amax4bits(dh);
      }
      #pragma unroll
      for (int m = 1; m < 64; m <<= 1) {
        const unsigned o0 = __shfl_xor(d0b, m), o1 = __shfl_xor(d1b, m);
        d0b = d0b > o0 ? d0b : o0;  d1b = d1b > o1 ? d1b : o1;
      }
      if (lane == 0) {
        // RELEASE: wave-level vmcnt(0) waits for ALL the wave's atomic swaps'
        // return values => h data is at the coherence point before flags issue.
        asm volatile("s_waitcnt vmcnt(0)" ::: "memory");
        const u64 tg = (u64)(unsigned)t << 32;
        __hip_atomic_store(p.flag0 + par*GRIDv + bid, tg | (u64)d0b,
                           __ATOMIC_RELAXED, __HIP_MEMORY_SCOPE_AGENT);
        __hip_atomic_store(p.flag1 + par*GRIDv + bid, tg | (u64)d1b,
                           __ATOMIC_RELAXED, __HIP_MEMORY_SCOPE_AGENT);
      }
    }

    // ---- flag barrier: 256 threads poll 256 blocks; no fences anywhere ----
    if (tid < GRIDv) {
      const u64 tag = (u64)(unsigned)t;
      u64 v;
      do { v = __hip_atomic_load(p.flag0 + par*GRIDv + tid,
                                 __ATOMIC_RELAXED, __HIP_MEMORY_SCOPE_AGENT); }
      while ((v >> 32) != tag);
      unsigned m0 = (unsigned)v;
      do { v = __hip_atomic_load(p.flag1 + par*GRIDv + tid,
                                 __ATOMIC_RELAXED, __HIP_MEMORY_SCOPE_AGENT); }
      while ((v >> 32) != tag);
      unsigned m1 = (unsigned)v;
      #pragma unroll
      for (int m = 1; m < 64; m <<= 1) {
        const unsigned o0 = __shfl_xor(m0, m), o1 = __shfl_xor(m1, m);
        m0 = m0 > o0 ? m0 : o0;  m1 = m1 > o1 ? m1 : o1;
      }
      if (lane == 0) { atomicMax(&dmax[par][0], m0); atomicMax(&dmax[par][1], m1); }
    }
    if (tid == THRv - 1) { dmax[par ^ 1][0] = 0u; dmax[par ^ 1][1] = 0u; }  // reset for next iter
    __syncthreads();

    const unsigned D0b = dmax[par][0];   // max|dh0(t)|
    const unsigned D1b = dmax[par][1];   // max|dh1(t-1)|
    if (t >= 2) {
      const unsigned Db = prevD0b > D1b ? prevD0b : D1b;  // D(t-1), NaN-bits sort high
      const float D = __uint_as_float(Db);
      if (!(D >= EPSc) || (t - 1) >= MAXST) { K = t - 1; break; }  // matches JAX cond
    }
    prevD0b = D0b;
    ++t;
  }

  // ---- output: out = h1(K) @ W_out^T + b_out (blocks 0..9, one output column each) ----
  __syncthreads();
  if (bid < NOUTv) {
    const float* h1f = (K & 1) ? p.h1b : p.h1a;
    const int o  = bid;
    const int b  = tid & 31;
    const int ig = tid >> 5;               // 16 i-slices of 64
    const float* wrow = p.W_out + o * NNv;
    float acc = 0.f;
    for (int qq = 0; qq < 8; ++qq) {
      const int i0 = (ig << 6) + qq * 8;
      const float* q0 = h1f + i0 * BSZ + b;
      float v0,v1,v2,v3,v4,v5,v6,v7;
      asm volatile(
        "global_load_dword %0, %8, off sc0 sc1\n\t"
        "global_load_dword %1, %8, off offset:128 sc0 sc1\n\t"
        "global_load_dword %2, %8, off offset:256 sc0 sc1\n\t"
        "global_load_dword %3, %8, off offset:384 sc0 sc1\n\t"
        "global_load_dword %4, %8, off offset:512 sc0 sc1\n\t"
        "global_load_dword %5, %8, off offset:640 sc0 sc1\n\t"
        "global_load_dword %6, %8, off offset:768 sc0 sc1\n\t"
        "global_load_dword %7, %8, off offset:896 sc0 sc1\n\t"
        "s_waitcnt vmcnt(0)"
        : "=&v"(v0),"=&v"(v1),"=&v"(v2),"=&v"(v3),
          "=&v"(v4),"=&v"(v5),"=&v"(v6),"=&v"(v7)
        : "v"(q0) : "memory");
      acc = fmaf(v0, wrow[i0+0], acc);
      acc = fmaf(v1, wrow[i0+1], acc);
      acc = fmaf(v2, wrow[i0+2], acc);
      acc = fmaf(v3, wrow[i0+3], acc);
      acc = fmaf(v4, wrow[i0+4], acc);
      acc = fmaf(v5, wrow[i0+5], acc);
      acc = fmaf(v6, wrow[i0+6], acc);
      acc = fmaf(v7, wrow[i0+7], acc);
    }
    float* sr = wA;                        // weights no longer needed
    sr[ig*32 + b] = acc;
    __syncthreads();
    if (tid < 32) {
      float s = p.b_out[o];
      #pragma unroll
      for (int q = 0; q < 16; ++q) s += sr[q*32 + tid];
      p.out[tid*NOUTv + o] = s;            // out[b][o]
    }
  }
}

extern "C" void kernel_launch(void* const* d_in, const int* in_sizes, int n_in,
                              void* d_out, int out_size, void* d_ws, size_t ws_size,
                              hipStream_t stream) {
  const float* X       = (const float*)d_in[0];
  const float* W_input = (const float*)d_in[1];
  const float* b_input = (const float*)d_in[2];
  const float* W_in    = (const float*)d_in[3];
  const float* b_in    = (const float*)d_in[4];
  const float* W_rec   = (const float*)d_in[5];
  const float* mask    = (const float*)d_in[6];
  const float* b_rec   = (const float*)d_in[7];
  const float* W_out   = (const float*)d_in[8];
  const float* b_out   = (const float*)d_in[9];
  (void)in_sizes; (void)n_in; (void)out_size; (void)ws_size;

  float* ws = (float*)d_ws;
  Prm p;
  p.W_in  = W_in;  p.b_in  = b_in;  p.W_rec = W_rec; p.mask = mask;
  p.b_rec = b_rec; p.W_out = W_out; p.b_out = b_out;
  p.xin = ws + WS_XIN;
  p.h0a = ws + WS_H0A; p.h0b = ws + WS_H0B;
  p.h1a = ws + WS_H1A; p.h1b = ws + WS_H1B;
  p.flag0 = (u64*)(ws + WS_FLG);
  p.flag1 = p.flag0 + 2 * GRIDv;
  p.out  = (float*)d_out;

  k_xin<<<NNv, 256, 0, stream>>>(X, W_input, b_input,
                                 (float*)p.xin, p.h0a, p.h0b, p.h1a, p.h1b);
  k_main<<<GRIDv, THRv, 0, stream>>>(p);
}